// Round 7
// baseline (185.936 us; speedup 1.0000x reference)
//
#include <hip/hip_runtime.h>
#include <hip/hip_bf16.h>

// B=2, T=2048, C=1024, H=16, D=64. bf16 in/out (runtime dtype detect, inline per block).
// k_prep (transpose w [+convert x if fp32]) -> k_gemm_qkv (BK=64, XOR-swizzled LDS,
// XCD-swizzled grid, Q,K -> qk[t][2C], V^T -> vtg[b,h,d,T]) -> k_attn v7: NO LDS
// staging. K/V MFMA fragments load directly from global (L2-resident: head-locked
// grid puts each XCD's 4 heads' K+V = 2MB in its 4MB L2). No in-loop barriers ->
// waves fully independent; K pipelined 1 trip ahead in regs; V issued at trip top,
// consumed after QK+softmax. LDS only holds the 17.7KB epilogue merge buffer.
// Block = 4 waves = (2 q-bands of 32 rows) x (2 kv parities); fixed-max softmax
// makes the cross-parity merge additive. Grid (32 bh, 32 g); g=31-y longest-first.
// launch_bounds(256,4): (256,6) spilled in R5 (VGPR 60->40, WRITE 16->264MB, 3x).
// ws: xb@0(8MB); wt@8MB(6MB); qk@16MB(16MB); vtg@32MB(8MB)

#define CDIM  1024
#define C3    3072
#define HS    64
#define TLEN  2048
#define KVT   64         // kv per trip
#define SCL   0.1803368801111204f   // (1/8) * log2(e)

typedef __attribute__((ext_vector_type(8))) short bf16x8;
typedef __attribute__((ext_vector_type(4))) float f32x4;
typedef __attribute__((ext_vector_type(4))) unsigned short u16x4;

__device__ __forceinline__ unsigned short f2b(float f) {
    unsigned u = __float_as_uint(f);
    unsigned r = (u + 0x7FFFu + ((u >> 16) & 1u)) >> 16;
    return (unsigned short)r;
}
__device__ __forceinline__ float b2f(unsigned short u) {
    return __uint_as_float(((unsigned)u) << 16);
}
__device__ __forceinline__ float fexp2(float x) {
    return __builtin_amdgcn_exp2f(x);
}
__device__ __forceinline__ unsigned pkbf(float a, float b) {
    float2 f; f.x = a; f.y = b;
    __hip_bfloat162 h = __float22bfloat162_rn(f);
    union { __hip_bfloat162 h2; unsigned u; } c;
    c.h2 = h;
    return c.u;
}
__device__ __forceinline__ void gl_lds16(const unsigned short* g, unsigned short* l) {
    __builtin_amdgcn_global_load_lds((const __attribute__((address_space(1))) void*)g,
                                     (__attribute__((address_space(3))) void*)l, 16, 0, 0);
}
// bf16 iff "exponent" bits of low halfword concentrate in the normal range.
__device__ __forceinline__ int detect_bf(const void* bias, int lane) {
    unsigned w = ((const unsigned*)bias)[lane];
    unsigned e = (w >> 7) & 0xFF;
    unsigned long long m = __ballot(e >= 100 && e <= 135);
    return __popcll(m) >= 48;
}

// In-register S^T -> PV-B-fragment exchange.
// Input x at lane(l16,quad'): packed bf16 pair for kv = nt*16 + quad'*4 + {2pr,2pr+1}, q=l16.
// plswap produces y0 = rows (q0,q2,q0,q2), y1 = rows (q1,q3,q1,q3) of x:
// dest quad q reads y0 -> source quad 2(q&1); y1 -> source quad 2(q&1)+1.
__device__ __forceinline__ void plswap(unsigned x, unsigned& y0, unsigned& y1) {
    unsigned aa = x, bb = x;
    asm("v_permlane32_swap_b32 %0, %1" : "+v"(aa), "+v"(bb));
    asm("v_permlane16_swap_b32 %0, %1" : "+v"(aa), "+v"(bb));
    y0 = aa; y1 = bb;
}
// B-fragment dword r needs sp[nt=(quad>>1)][r&1] from source quad 2(quad&1)+(r>>1).
__device__ __forceinline__ bf16x8 xfrag(unsigned x00, unsigned x01,
                                        unsigned x10, unsigned x11, int qsel) {
    unsigned y000, y100, y001, y101, y010, y110, y011, y111;
    plswap(x00, y000, y100);
    plswap(x01, y001, y101);
    plswap(x10, y010, y110);
    plswap(x11, y011, y111);
    union { unsigned u[4]; bf16x8 v; } r;
    r.u[0] = qsel ? y010 : y000;   // pr=0, quad' = 2(q&1)
    r.u[1] = qsel ? y011 : y001;   // pr=1, quad' = 2(q&1)
    r.u[2] = qsel ? y110 : y100;   // pr=0, quad' = 2(q&1)+1
    r.u[3] = qsel ? y111 : y101;   // pr=1, quad' = 2(q&1)+1
    return r.v;
}

// prep: blocks 0..767 transpose w tile; all 2048 blocks convert an x stripe if fp32.
__global__ __launch_bounds__(256) void k_prep(const void* __restrict__ w,
                                              const void* __restrict__ x,
                                              const void* __restrict__ bias,
                                              unsigned short* __restrict__ wt,
                                              unsigned short* __restrict__ xb) {
    __shared__ unsigned short tile[64 * 66];
    int t = threadIdx.x;
    int isbf = detect_bf(bias, t & 63);
    int bid = blockIdx.x;

    if (bid < 768) {
        int n0 = (bid % 48) * 64;
        int k0 = (bid / 48) * 64;
        for (int i = 0; i < 16; ++i) {
            int idx = t + i * 256;
            int r = idx >> 6, c = idx & 63;
            unsigned short v;
            if (isbf) v = ((const unsigned short*)w)[(k0 + r) * C3 + n0 + c];
            else      v = f2b(((const float*)w)[(k0 + r) * C3 + n0 + c]);
            tile[r * 66 + c] = v;
        }
        __syncthreads();
        for (int i = 0; i < 16; ++i) {
            int idx = t + i * 256;
            int r = idx >> 6, c = idx & 63;
            wt[(n0 + r) * CDIM + k0 + c] = tile[c * 66 + r];
        }
    }
    if (!isbf) {
        const float* s = (const float*)x;
        unsigned* d = (unsigned*)xb;
        int base = bid * 1024;
        for (int j = t; j < 1024; j += 256) {
            int idx = base + j;
            float a = s[2 * idx], b = s[2 * idx + 1];
            d[idx] = (unsigned)f2b(a) | ((unsigned)f2b(b) << 16);
        }
    }
}

// GEMM: qkv = x @ w + bias. BK=64, XOR-swizzled LDS (slot kc holds chunk kc^(row&7)).
// XCD-swizzled grid (768 blocks, 768%8==0 -> bijective). Q,K -> qk[t][2048];
// V -> vtg[((b*16+h)*64+d)][2048]
__global__ __launch_bounds__(256, 3) void k_gemm_qkv(const void* __restrict__ xraw,
                                                     const unsigned short* __restrict__ xb,
                                                     const void* __restrict__ biasraw,
                                                     const unsigned short* __restrict__ Bt,
                                                     unsigned short* __restrict__ qk,
                                                     unsigned short* __restrict__ vtg) {
    __shared__ __align__(16) unsigned short As[128 * 64];
    __shared__ __align__(16) unsigned short Bs[128 * 64];
    int tid  = threadIdx.x;
    int lane = tid & 63, wv = tid >> 6;
    int quad = lane >> 4, l16 = lane & 15;
    int isbf = detect_bf(biasraw, lane);
    const unsigned short* A = isbf ? (const unsigned short*)xraw : xb;

    // XCD-aware bijective swizzle: 768 blocks, 8 XCDs, 96 per XCD chunk.
    int lin = blockIdx.x + 24 * blockIdx.y;
    int swz = (lin & 7) * 96 + (lin >> 3);
    int m0 = (swz / 24) * 128, n0 = (swz % 24) * 128;
    int wm = (wv >> 1) * 64, wn = (wv & 1) * 64;

    f32x4 acc[4][4] = {};

    int srow = wv * 8 + (lane >> 3);
    int kcg8 = (((lane & 7) ^ (lane >> 3)) * 8);
    const unsigned short* Ag = A  + (m0 + srow) * CDIM + kcg8;
    const unsigned short* Bg = Bt + (n0 + srow) * CDIM + kcg8;
    unsigned short* lA = &As[srow * 64 + (lane & 7) * 8];
    unsigned short* lB = &Bs[srow * 64 + (lane & 7) * 8];

    for (int k0 = 0; k0 < CDIM; k0 += 64) {
        __syncthreads();
        for (int j = 0; j < 4; ++j) {
            gl_lds16(Ag + j * (32 * CDIM), lA + j * (32 * 64));
            gl_lds16(Bg + j * (32 * CDIM), lB + j * (32 * 64));
        }
        Ag += 64; Bg += 64;
        __syncthreads();

        for (int kk = 0; kk < 2; ++kk) {
            int sw = (l16 & 7);
            bf16x8 af[4], bfr[4];
            for (int mt = 0; mt < 4; ++mt)
                af[mt] = *(const bf16x8*)&As[(wm + mt * 16 + l16) * 64 + (((kk * 4 + quad) ^ sw) * 8)];
            for (int nt = 0; nt < 4; ++nt)
                bfr[nt] = *(const bf16x8*)&Bs[(wn + nt * 16 + l16) * 64 + (((kk * 4 + quad) ^ sw) * 8)];
            for (int mt = 0; mt < 4; ++mt)
                for (int nt = 0; nt < 4; ++nt)
                    acc[mt][nt] = __builtin_amdgcn_mfma_f32_16x16x32_bf16(af[mt], bfr[nt], acc[mt][nt], 0, 0, 0);
        }
    }

    if (n0 < 2048) {
        for (int mt = 0; mt < 4; ++mt) {
            int row = m0 + wm + mt * 16 + quad * 4;
            for (int nt = 0; nt < 4; ++nt) {
                int col = n0 + wn + nt * 16 + l16;
                float bv = isbf ? b2f(((const unsigned short*)biasraw)[col])
                                : ((const float*)biasraw)[col];
                for (int i = 0; i < 4; ++i)
                    qk[(row + i) * 2048 + col] = f2b(acc[mt][nt][i] + bv);
            }
        }
    } else {
        for (int mt = 0; mt < 4; ++mt) {
            int row = m0 + wm + mt * 16 + quad * 4;
            int t = row & 2047, b = row >> 11;
            for (int nt = 0; nt < 4; ++nt) {
                int col = n0 + wn + nt * 16 + l16;
                float bv = isbf ? b2f(((const unsigned short*)biasraw)[col])
                                : ((const float*)biasraw)[col];
                int hh = (col - 2048) >> 6, d = (col - 2048) & 63;
                u16x4 pk;
                for (int i = 0; i < 4; ++i) pk[i] = f2b(acc[mt][nt][i] + bv);
                *(u16x4*)&vtg[((b * 16 + hh) * 64 + d) * TLEN + t] = pk;
            }
        }
    }
}

// Split-kv causal flash attention v7. Grid (32 bh, 32 y), 4 waves/block, 256 thr.
// g = 31-y; block owns q rows [64g, 64g+64). Wave wv: band s=wv>>1 (32 rows at
// qbase=64g+32s), kv parity p=wv&1. Trip t covers kv [64t+32p, 64t+32p+32).
// NO LDS staging, NO in-loop barriers: K/V fragments read directly from L2-resident
// global (16B/lane, 16 rows x 64B segments). K pipelined 1 trip ahead in registers;
// V issued at trip top, consumed after QK+softmax (~300cy later). Wave (s=0,p=1)
// runs T-1 trips. Epilogue: p=1 waves write partial O (f32) + l to LDS; p=0 adds,
// normalizes, stores (fixed-max softmax partials share the same scale).
__global__ __launch_bounds__(256, 4) void k_attn(const unsigned short* __restrict__ qk,
                                                 const unsigned short* __restrict__ vtg,
                                                 const void* __restrict__ biasraw,
                                                 void* __restrict__ outv) {
    __shared__ __align__(16) float SMf[4416];   // merge 2*32*68 + 64 lsum

    int tid  = threadIdx.x;
    int lane = tid & 63, wv = tid >> 6;            // wv 0..3
    int quad = lane >> 4, l16 = lane & 15;
    int isbf = detect_bf(biasraw, lane);
    int bh = blockIdx.x;
    int g  = 31 - blockIdx.y;                      // longest blocks dispatch first
    int b = bh >> 4, h = bh & 15;
    int rowbase = b * TLEN;

    int s_ = wv >> 1;                              // q sub-band (0/1)
    int p  = wv & 1;                               // kv parity
    int qbase = 64 * g + 32 * s_;
    int T  = g + 1;
    int Tw = T - ((s_ == 0 && p == 1) ? 1 : 0);    // (0,1) skips the diagonal trip
    bool dmw = (p == s_);                          // wave masks on its last trip

    bf16x8 qf[2][2];
    for (int qt = 0; qt < 2; ++qt)
        for (int kh = 0; kh < 2; ++kh)
            qf[qt][kh] = *(const bf16x8*)&qk[(rowbase + qbase + qt * 16 + l16) * 2048
                                            + h * HS + kh * 32 + quad * 8];

    f32x4 o[2][4] = {};
    float ls[2] = {0.f, 0.f};

    // per-lane fragment pointers (running, advance per trip)
    const unsigned short* kp0 = qk + (rowbase + 32 * p + l16) * 2048 + CDIM + h * HS + quad * 8;
    const unsigned short* kp1 = kp0 + 16 * 2048;
    const unsigned short* vpb = vtg + (bh * 64 + l16) * 2048 + 32 * p + quad * 8;
    const unsigned short* vp0 = vpb;
    const unsigned short* vp1 = vpb + 16 * 2048;
    const unsigned short* vp2 = vpb + 32 * 2048;
    const unsigned short* vp3 = vpb + 48 * 2048;

    // prologue: K fragments for trip 0
    bf16x8 kA00, kA01, kA10, kA11;
    if (Tw > 0) {
        kA00 = *(const bf16x8*)kp0; kA01 = *(const bf16x8*)(kp0 + 32);
        kA10 = *(const bf16x8*)kp1; kA11 = *(const bf16x8*)(kp1 + 32);
        kp0 += KVT * 2048; kp1 += KVT * 2048;
    }

    for (int t = 0; t < Tw; ++t) {
        // V fragments for this trip: issue now, consumed after QK+softmax
        bf16x8 av0 = *(const bf16x8*)vp0;
        bf16x8 av1 = *(const bf16x8*)vp1;
        bf16x8 av2 = *(const bf16x8*)vp2;
        bf16x8 av3 = *(const bf16x8*)vp3;
        vp0 += KVT; vp1 += KVT; vp2 += KVT; vp3 += KVT;

        // S^T = K.Q^T: both q-fragments share every K fragment
        f32x4 sv[2][2];
        __builtin_amdgcn_s_setprio(1);
        #pragma unroll
        for (int qt = 0; qt < 2; ++qt) {
            f32x4 z0 = {};
            z0 = __builtin_amdgcn_mfma_f32_16x16x32_bf16(kA00, qf[qt][0], z0, 0, 0, 0);
            z0 = __builtin_amdgcn_mfma_f32_16x16x32_bf16(kA01, qf[qt][1], z0, 0, 0, 0);
            sv[qt][0] = z0;
            f32x4 z1 = {};
            z1 = __builtin_amdgcn_mfma_f32_16x16x32_bf16(kA10, qf[qt][0], z1, 0, 0, 0);
            z1 = __builtin_amdgcn_mfma_f32_16x16x32_bf16(kA11, qf[qt][1], z1, 0, 0, 0);
            sv[qt][1] = z1;
        }
        __builtin_amdgcn_s_setprio(0);

        // prefetch next trip's K fragments (hide L2 latency under softmax+PV)
        bf16x8 kB00, kB01, kB10, kB11;
        bool pf = (t + 1 < Tw);
        if (pf) {
            kB00 = *(const bf16x8*)kp0; kB01 = *(const bf16x8*)(kp0 + 32);
            kB10 = *(const bf16x8*)kp1; kB11 = *(const bf16x8*)(kp1 + 32);
            kp0 += KVT * 2048; kp1 += KVT * 2048;
        }

        // fixed-max softmax: pv = 2^(s*SCL - 12); exact after normalization.
        // Mask branch hoisted: wave-uniform, taken only on this wave's diagonal trip.
        unsigned sp[2][2][2];
        int kvb = t * KVT + 32 * p;
        if (dmw && (t == T - 1)) {
            #pragma unroll
            for (int qt = 0; qt < 2; ++qt) {
                float psum = 0.f;
                int q = qbase + qt * 16 + l16;
                #pragma unroll
                for (int nt = 0; nt < 2; ++nt) {
                    float pv[4];
                    #pragma unroll
                    for (int i = 0; i < 4; ++i) {
                        float arg = fminf(fmaf(sv[qt][nt][i], SCL, -12.0f), 30.0f);
                        int kv = kvb + nt * 16 + quad * 4 + i;
                        if (kv > q) arg = -1e30f;
                        pv[i] = fexp2(arg);
                        psum += pv[i];
                    }
                    sp[qt][nt][0] = pkbf(pv[0], pv[1]);
                    sp[qt][nt][1] = pkbf(pv[2], pv[3]);
                }
                ls[qt] += psum;
            }
        } else {
            #pragma unroll
            for (int qt = 0; qt < 2; ++qt) {
                float psum = 0.f;
                #pragma unroll
                for (int nt = 0; nt < 2; ++nt) {
                    float pv[4];
                    #pragma unroll
                    for (int i = 0; i < 4; ++i) {
                        float arg = fminf(fmaf(sv[qt][nt][i], SCL, -12.0f), 30.0f);
                        pv[i] = fexp2(arg);
                        psum += pv[i];
                    }
                    sp[qt][nt][0] = pkbf(pv[0], pv[1]);
                    sp[qt][nt][1] = pkbf(pv[2], pv[3]);
                }
                ls[qt] += psum;
            }
        }

        // O^T += V^T.P^T; V fragment feeds both q-fragments
        int qsel = quad & 2;
        bf16x8 f0 = xfrag(sp[0][0][0], sp[0][0][1], sp[0][1][0], sp[0][1][1], qsel);
        bf16x8 f1 = xfrag(sp[1][0][0], sp[1][0][1], sp[1][1][0], sp[1][1][1], qsel);
        __builtin_amdgcn_s_setprio(1);
        o[0][0] = __builtin_amdgcn_mfma_f32_16x16x32_bf16(av0, f0, o[0][0], 0, 0, 0);
        o[1][0] = __builtin_amdgcn_mfma_f32_16x16x32_bf16(av0, f1, o[1][0], 0, 0, 0);
        o[0][1] = __builtin_amdgcn_mfma_f32_16x16x32_bf16(av1, f0, o[0][1], 0, 0, 0);
        o[1][1] = __builtin_amdgcn_mfma_f32_16x16x32_bf16(av1, f1, o[1][1], 0, 0, 0);
        o[0][2] = __builtin_amdgcn_mfma_f32_16x16x32_bf16(av2, f0, o[0][2], 0, 0, 0);
        o[1][2] = __builtin_amdgcn_mfma_f32_16x16x32_bf16(av2, f1, o[1][2], 0, 0, 0);
        o[0][3] = __builtin_amdgcn_mfma_f32_16x16x32_bf16(av3, f0, o[0][3], 0, 0, 0);
        o[1][3] = __builtin_amdgcn_mfma_f32_16x16x32_bf16(av3, f1, o[1][3], 0, 0, 0);
        __builtin_amdgcn_s_setprio(0);

        if (pf) { kA00 = kB00; kA01 = kB01; kA10 = kB10; kA11 = kB11; }
    }

    // merge the two kv-parity partials (additive: same fixed-max scale), normalize, store
    #pragma unroll
    for (int qt = 0; qt < 2; ++qt) {
        ls[qt] += __shfl_xor(ls[qt], 16);
        ls[qt] += __shfl_xor(ls[qt], 32);
    }
    float* mrg  = SMf;                 // [2 bands][32 q][68] floats = 17408B
    float* lbuf = SMf + 4352;          // [2 bands][32 q] floats

    if (p == 1) {
        #pragma unroll
        for (int qt = 0; qt < 2; ++qt)
            #pragma unroll
            for (int dt = 0; dt < 4; ++dt)
                *(f32x4*)&mrg[s_ * (32 * 68) + (qt * 16 + l16) * 68 + dt * 16 + quad * 4] = o[qt][dt];
        if (quad == 0) {
            lbuf[s_ * 32 + l16]      = ls[0];
            lbuf[s_ * 32 + 16 + l16] = ls[1];
        }
    }
    __syncthreads();
    if (p == 0) {
        #pragma unroll
        for (int qt = 0; qt < 2; ++qt) {
            float lt = ls[qt] + lbuf[s_ * 32 + qt * 16 + l16];
            float inv = 1.0f / lt;
            int q = qbase + qt * 16 + l16;
            if (isbf) {
                unsigned short* out = (unsigned short*)outv;
                #pragma unroll
                for (int dt = 0; dt < 4; ++dt) {
                    f32x4 m = *(const f32x4*)&mrg[s_ * (32 * 68) + (qt * 16 + l16) * 68 + dt * 16 + quad * 4];
                    u16x4 ov;
                    #pragma unroll
                    for (int i = 0; i < 4; ++i) ov[i] = f2b((o[qt][dt][i] + m[i]) * inv);
                    *(u16x4*)&out[(rowbase + q) * CDIM + h * HS + dt * 16 + quad * 4] = ov;
                }
            } else {
                float* out = (float*)outv;
                #pragma unroll
                for (int dt = 0; dt < 4; ++dt) {
                    f32x4 m = *(const f32x4*)&mrg[s_ * (32 * 68) + (qt * 16 + l16) * 68 + dt * 16 + quad * 4];
                    float4 ov;
                    ov.x = (o[qt][dt][0] + m[0]) * inv;
                    ov.y = (o[qt][dt][1] + m[1]) * inv;
                    ov.z = (o[qt][dt][2] + m[2]) * inv;
                    ov.w = (o[qt][dt][3] + m[3]) * inv;
                    *(float4*)&out[(rowbase + q) * CDIM + h * HS + dt * 16 + quad * 4] = ov;
                }
            }
        }
    }
}

extern "C" void kernel_launch(void* const* d_in, const int* in_sizes, int n_in,
                              void* d_out, int out_size, void* d_ws, size_t ws_size,
                              hipStream_t stream) {
    const void* x    = d_in[0];
    const void* w    = d_in[1];
    const void* bias = d_in[2];

    char* ws = (char*)d_ws;
    unsigned short* xb  = (unsigned short*)ws;                   // 8 MB (fp32 path only)
    unsigned short* wt  = (unsigned short*)(ws + (8u  << 20));   // 6 MB
    unsigned short* qk  = (unsigned short*)(ws + (16u << 20));   // 16 MB
    unsigned short* vtg = (unsigned short*)(ws + (32u << 20));   // 8 MB

    k_prep<<<2048, 256, 0, stream>>>(w, x, bias, wt, xb);
    k_gemm_qkv<<<dim3(24, 32), 256, 0, stream>>>(x, xb, bias, wt, qk, vtg);
    k_attn<<<dim3(32, 32), 256, 0, stream>>>(qk, vtg, bias, d_out);
}

// Round 8
// 149.197 us; speedup vs baseline: 1.2463x; 1.2463x over previous
//
#include <hip/hip_runtime.h>
#include <hip/hip_bf16.h>

// B=2, T=2048, C=1024, H=16, D=64. bf16 in/out (runtime dtype detect, inline per block).
// k_prep (transpose w [+convert x if fp32]) -> k_gemm_qkv (BK=64, XOR-swizzled LDS,
// XCD-swizzled grid, Q,K -> qk[t][2C], V^T -> vtg[b,h,d,T]) -> k_attn v8: v6 skeleton
// (split-kv, single-buffer LDS, 2 barriers/trip) with global_load_lds staging
// (no register round-trip, no ds_writes), gemm-style both-sides XOR swizzle
// (linear LDS dest for gl_lds; slot = chunk ^ (row&7); 2-way conflicts only), and
// trip-invariant precomputed LDS read addresses (zero in-loop address VALU).
// Order per trip: Kfrag reads -> QK -> Vfrag reads -> barrier -> issue gl_lds(t+1)
// -> softmax+xfrag+PV (hides DMA) -> barrier (vmcnt drain).
// R7 lesson: direct per-lane L2 fragment loads = 16 scattered 64B lines/instr ->
// latency-bound (80us). R5 lesson: launch_bounds(256,6) spills -> keep (256,4).
// ws: xb@0(8MB); wt@8MB(6MB); qk@16MB(16MB); vtg@32MB(8MB)

#define CDIM  1024
#define C3    3072
#define HS    64
#define TLEN  2048
#define KVT   64         // kv per trip
#define SCL   0.1803368801111204f   // (1/8) * log2(e)

typedef __attribute__((ext_vector_type(8))) short bf16x8;
typedef __attribute__((ext_vector_type(4))) float f32x4;
typedef __attribute__((ext_vector_type(4))) unsigned short u16x4;

__device__ __forceinline__ unsigned short f2b(float f) {
    unsigned u = __float_as_uint(f);
    unsigned r = (u + 0x7FFFu + ((u >> 16) & 1u)) >> 16;
    return (unsigned short)r;
}
__device__ __forceinline__ float b2f(unsigned short u) {
    return __uint_as_float(((unsigned)u) << 16);
}
__device__ __forceinline__ float fexp2(float x) {
    return __builtin_amdgcn_exp2f(x);
}
__device__ __forceinline__ unsigned pkbf(float a, float b) {
    float2 f; f.x = a; f.y = b;
    __hip_bfloat162 h = __float22bfloat162_rn(f);
    union { __hip_bfloat162 h2; unsigned u; } c;
    c.h2 = h;
    return c.u;
}
__device__ __forceinline__ void gl_lds16(const unsigned short* g, unsigned short* l) {
    __builtin_amdgcn_global_load_lds((const __attribute__((address_space(1))) void*)g,
                                     (__attribute__((address_space(3))) void*)l, 16, 0, 0);
}
// bf16 iff "exponent" bits of low halfword concentrate in the normal range.
__device__ __forceinline__ int detect_bf(const void* bias, int lane) {
    unsigned w = ((const unsigned*)bias)[lane];
    unsigned e = (w >> 7) & 0xFF;
    unsigned long long m = __ballot(e >= 100 && e <= 135);
    return __popcll(m) >= 48;
}

// In-register S^T -> PV-B-fragment exchange.
// Input x at lane(l16,quad'): packed bf16 pair for kv = nt*16 + quad'*4 + {2pr,2pr+1}, q=l16.
__device__ __forceinline__ void plswap(unsigned x, unsigned& y0, unsigned& y1) {
    unsigned aa = x, bb = x;
    asm("v_permlane32_swap_b32 %0, %1" : "+v"(aa), "+v"(bb));
    asm("v_permlane16_swap_b32 %0, %1" : "+v"(aa), "+v"(bb));
    y0 = aa; y1 = bb;
}
// B-fragment dword r needs sp[nt=(quad>>1)][r&1] from source quad 2(quad&1)+(r>>1).
__device__ __forceinline__ bf16x8 xfrag(unsigned x00, unsigned x01,
                                        unsigned x10, unsigned x11, int qsel) {
    unsigned y000, y100, y001, y101, y010, y110, y011, y111;
    plswap(x00, y000, y100);
    plswap(x01, y001, y101);
    plswap(x10, y010, y110);
    plswap(x11, y011, y111);
    union { unsigned u[4]; bf16x8 v; } r;
    r.u[0] = qsel ? y010 : y000;   // pr=0, quad' = 2(q&1)
    r.u[1] = qsel ? y011 : y001;   // pr=1, quad' = 2(q&1)
    r.u[2] = qsel ? y110 : y100;   // pr=0, quad' = 2(q&1)+1
    r.u[3] = qsel ? y111 : y101;   // pr=1, quad' = 2(q&1)+1
    return r.v;
}

// prep: blocks 0..767 transpose w tile; all 2048 blocks convert an x stripe if fp32.
__global__ __launch_bounds__(256) void k_prep(const void* __restrict__ w,
                                              const void* __restrict__ x,
                                              const void* __restrict__ bias,
                                              unsigned short* __restrict__ wt,
                                              unsigned short* __restrict__ xb) {
    __shared__ unsigned short tile[64 * 66];
    int t = threadIdx.x;
    int isbf = detect_bf(bias, t & 63);
    int bid = blockIdx.x;

    if (bid < 768) {
        int n0 = (bid % 48) * 64;
        int k0 = (bid / 48) * 64;
        for (int i = 0; i < 16; ++i) {
            int idx = t + i * 256;
            int r = idx >> 6, c = idx & 63;
            unsigned short v;
            if (isbf) v = ((const unsigned short*)w)[(k0 + r) * C3 + n0 + c];
            else      v = f2b(((const float*)w)[(k0 + r) * C3 + n0 + c]);
            tile[r * 66 + c] = v;
        }
        __syncthreads();
        for (int i = 0; i < 16; ++i) {
            int idx = t + i * 256;
            int r = idx >> 6, c = idx & 63;
            wt[(n0 + r) * CDIM + k0 + c] = tile[c * 66 + r];
        }
    }
    if (!isbf) {
        const float* s = (const float*)x;
        unsigned* d = (unsigned*)xb;
        int base = bid * 1024;
        for (int j = t; j < 1024; j += 256) {
            int idx = base + j;
            float a = s[2 * idx], b = s[2 * idx + 1];
            d[idx] = (unsigned)f2b(a) | ((unsigned)f2b(b) << 16);
        }
    }
}

// GEMM: qkv = x @ w + bias. BK=64, XOR-swizzled LDS (slot kc holds chunk kc^(row&7)).
// XCD-swizzled grid (768 blocks, 768%8==0 -> bijective). Q,K -> qk[t][2048];
// V -> vtg[((b*16+h)*64+d)][2048]
__global__ __launch_bounds__(256, 3) void k_gemm_qkv(const void* __restrict__ xraw,
                                                     const unsigned short* __restrict__ xb,
                                                     const void* __restrict__ biasraw,
                                                     const unsigned short* __restrict__ Bt,
                                                     unsigned short* __restrict__ qk,
                                                     unsigned short* __restrict__ vtg) {
    __shared__ __align__(16) unsigned short As[128 * 64];
    __shared__ __align__(16) unsigned short Bs[128 * 64];
    int tid  = threadIdx.x;
    int lane = tid & 63, wv = tid >> 6;
    int quad = lane >> 4, l16 = lane & 15;
    int isbf = detect_bf(biasraw, lane);
    const unsigned short* A = isbf ? (const unsigned short*)xraw : xb;

    // XCD-aware bijective swizzle: 768 blocks, 8 XCDs, 96 per XCD chunk.
    int lin = blockIdx.x + 24 * blockIdx.y;
    int swz = (lin & 7) * 96 + (lin >> 3);
    int m0 = (swz / 24) * 128, n0 = (swz % 24) * 128;
    int wm = (wv >> 1) * 64, wn = (wv & 1) * 64;

    f32x4 acc[4][4] = {};

    int srow = wv * 8 + (lane >> 3);
    int kcg8 = (((lane & 7) ^ (lane >> 3)) * 8);
    const unsigned short* Ag = A  + (m0 + srow) * CDIM + kcg8;
    const unsigned short* Bg = Bt + (n0 + srow) * CDIM + kcg8;
    unsigned short* lA = &As[srow * 64 + (lane & 7) * 8];
    unsigned short* lB = &Bs[srow * 64 + (lane & 7) * 8];

    for (int k0 = 0; k0 < CDIM; k0 += 64) {
        __syncthreads();
        for (int j = 0; j < 4; ++j) {
            gl_lds16(Ag + j * (32 * CDIM), lA + j * (32 * 64));
            gl_lds16(Bg + j * (32 * CDIM), lB + j * (32 * 64));
        }
        Ag += 64; Bg += 64;
        __syncthreads();

        for (int kk = 0; kk < 2; ++kk) {
            int sw = (l16 & 7);
            bf16x8 af[4], bfr[4];
            for (int mt = 0; mt < 4; ++mt)
                af[mt] = *(const bf16x8*)&As[(wm + mt * 16 + l16) * 64 + (((kk * 4 + quad) ^ sw) * 8)];
            for (int nt = 0; nt < 4; ++nt)
                bfr[nt] = *(const bf16x8*)&Bs[(wn + nt * 16 + l16) * 64 + (((kk * 4 + quad) ^ sw) * 8)];
            for (int mt = 0; mt < 4; ++mt)
                for (int nt = 0; nt < 4; ++nt)
                    acc[mt][nt] = __builtin_amdgcn_mfma_f32_16x16x32_bf16(af[mt], bfr[nt], acc[mt][nt], 0, 0, 0);
        }
    }

    if (n0 < 2048) {
        for (int mt = 0; mt < 4; ++mt) {
            int row = m0 + wm + mt * 16 + quad * 4;
            for (int nt = 0; nt < 4; ++nt) {
                int col = n0 + wn + nt * 16 + l16;
                float bv = isbf ? b2f(((const unsigned short*)biasraw)[col])
                                : ((const float*)biasraw)[col];
                for (int i = 0; i < 4; ++i)
                    qk[(row + i) * 2048 + col] = f2b(acc[mt][nt][i] + bv);
            }
        }
    } else {
        for (int mt = 0; mt < 4; ++mt) {
            int row = m0 + wm + mt * 16 + quad * 4;
            int t = row & 2047, b = row >> 11;
            for (int nt = 0; nt < 4; ++nt) {
                int col = n0 + wn + nt * 16 + l16;
                float bv = isbf ? b2f(((const unsigned short*)biasraw)[col])
                                : ((const float*)biasraw)[col];
                int hh = (col - 2048) >> 6, d = (col - 2048) & 63;
                u16x4 pk;
                for (int i = 0; i < 4; ++i) pk[i] = f2b(acc[mt][nt][i] + bv);
                *(u16x4*)&vtg[((b * 16 + hh) * 64 + d) * TLEN + t] = pk;
            }
        }
    }
}

// Split-kv causal flash attention v8. Grid (32 bh, 32 y), 4 waves/block, 256 thr.
// g = 31-y; block owns q rows [64g, 64g+64). Wave wv: band s=wv>>1 (32 rows at
// qbase=64g+32s), kv parity p=wv&1. Trip t covers kv [64t, 64t+64); T = g+1 trips.
// Single-buffer K[64][64] + V^T[64][64] in LDS, staged by global_load_lds with
// gemm-style XOR swizzle (slot = chunk ^ (row&7), pre-swizzled source). Frag read
// addresses trip-invariant (precomputed VGPRs). 2 barriers/trip; gl_lds for t+1
// issued right after the read-barrier, drains under softmax+PV at the end-barrier.
// Epilogue: p=1 waves write partial O (f32) + l to LDS; p=0 adds, normalizes, stores
// (fixed-max softmax partials share the same scale).
__global__ __launch_bounds__(256, 4) void k_attn(const unsigned short* __restrict__ qk,
                                                 const unsigned short* __restrict__ vtg,
                                                 const void* __restrict__ biasraw,
                                                 void* __restrict__ outv) {
    __shared__ __align__(16) float SMf[4416];    // 17664B: staging 16KB / merge 17.4KB alias
    unsigned short* Ks = (unsigned short*)SMf;   // [64][64] linear, swizzled slots
    unsigned short* Vt = Ks + 4096;              // [64][64] linear, swizzled slots

    int tid  = threadIdx.x;
    int lane = tid & 63, wv = tid >> 6;            // wv 0..3
    int quad = lane >> 4, l16 = lane & 15;
    int isbf = detect_bf(biasraw, lane);
    int bh = blockIdx.x;
    int g  = 31 - blockIdx.y;                      // longest blocks dispatch first
    int b = bh >> 4, h = bh & 15;
    int rowbase = b * TLEN;

    int s_ = wv >> 1;                              // q sub-band (0/1)
    int p  = wv & 1;                               // kv parity
    int qbase = 64 * g + 32 * s_;
    int T = g + 1;

    bf16x8 qf[2][2];
    for (int qt = 0; qt < 2; ++qt)
        for (int kh = 0; kh < 2; ++kh)
            qf[qt][kh] = *(const bf16x8*)&qk[(rowbase + qbase + qt * 16 + l16) * 2048
                                            + h * HS + kh * 32 + quad * 8];

    f32x4 o[2][4] = {};
    float ls[2] = {0.f, 0.f};

    // ---- staging map (per thread): 2 gl_lds for K + 2 for V, 16B each ----
    int lr  = lane >> 3;                 // 0..7 (row within wave-section, == row&7)
    int ls8 = lane & 7;                  // LDS slot index
    int srow = wv * 8 + lr;              // 0..31
    int schunk = (ls8 ^ lr) * 8;         // pre-swizzled source chunk (shorts)
    const unsigned short* srcK0 = qk  + (rowbase + srow) * 2048 + CDIM + h * HS + schunk;
    const unsigned short* srcK1 = srcK0 + 32 * 2048;
    const unsigned short* srcV0 = vtg + (bh * 64 + srow) * 2048 + schunk;
    const unsigned short* srcV1 = srcV0 + 32 * 2048;
    unsigned short* dK0 = Ks + srow * 64 + ls8 * 8;    // == wave base + lane*16B
    unsigned short* dK1 = dK0 + 32 * 64;
    unsigned short* dV0 = Vt + srow * 64 + ls8 * 8;
    unsigned short* dV1 = dV0 + 32 * 64;

    // ---- trip-invariant fragment read addresses (shorts) ----
    int sw = l16 & 7;
    int ka0 = (32 * p + l16) * 64 + ((quad ^ sw) * 8);           // K half0 (k-dim 0..31)
    int ka1 = (32 * p + l16) * 64 + (((4 + quad) ^ sw) * 8);     // K half1 (k-dim 32..63)
    int va  = l16 * 64 + (((4 * p + quad) ^ sw) * 8);            // V, cols 32p+quad*8

    // prologue: stage trip 0
    gl_lds16(srcK0, dK0); gl_lds16(srcK1, dK1);
    gl_lds16(srcV0, dV0); gl_lds16(srcV1, dV1);
    srcK0 += KVT * 2048; srcK1 += KVT * 2048;
    srcV0 += KVT;        srcV1 += KVT;
    __syncthreads();

    for (int t = 0; t < T; ++t) {
        bool act = (p == 0) || (s_ == 1) || (t < T - 1);   // (0,1) idles on last trip
        bool dm  = (t == T - 1) && (p == s_);              // diagonal-mask waves
        bool pf  = (t + 1 < T);

        f32x4 sv[2][2];
        bf16x8 av0, av1, av2, av3;
        if (act) {
            // K frags (swizzled slots; nt offset is a 2048B ds_read immediate)
            bf16x8 kf00 = *(const bf16x8*)&Ks[ka0];
            bf16x8 kf01 = *(const bf16x8*)&Ks[ka1];
            bf16x8 kf10 = *(const bf16x8*)&Ks[ka0 + 1024];
            bf16x8 kf11 = *(const bf16x8*)&Ks[ka1 + 1024];
            __builtin_amdgcn_s_setprio(1);
            #pragma unroll
            for (int qt = 0; qt < 2; ++qt) {
                f32x4 z0 = {};
                z0 = __builtin_amdgcn_mfma_f32_16x16x32_bf16(kf00, qf[qt][0], z0, 0, 0, 0);
                z0 = __builtin_amdgcn_mfma_f32_16x16x32_bf16(kf01, qf[qt][1], z0, 0, 0, 0);
                sv[qt][0] = z0;
                f32x4 z1 = {};
                z1 = __builtin_amdgcn_mfma_f32_16x16x32_bf16(kf10, qf[qt][0], z1, 0, 0, 0);
                z1 = __builtin_amdgcn_mfma_f32_16x16x32_bf16(kf11, qf[qt][1], z1, 0, 0, 0);
                sv[qt][1] = z1;
            }
            __builtin_amdgcn_s_setprio(0);
            // V frags (must complete before the read-barrier)
            av0 = *(const bf16x8*)&Vt[va];
            av1 = *(const bf16x8*)&Vt[va + 1024];
            av2 = *(const bf16x8*)&Vt[va + 2048];
            av3 = *(const bf16x8*)&Vt[va + 3072];
        }

        __syncthreads();   // all waves done reading trip t's K/V

        if (pf) {          // DMA trip t+1 into LDS; drains at the end-barrier
            gl_lds16(srcK0, dK0); gl_lds16(srcK1, dK1);
            gl_lds16(srcV0, dV0); gl_lds16(srcV1, dV1);
            srcK0 += KVT * 2048; srcK1 += KVT * 2048;
            srcV0 += KVT;        srcV1 += KVT;
        }

        if (act) {
            // fixed-max softmax: pv = 2^(s*SCL - 12); exact after normalization
            unsigned sp[2][2][2];
            int kvb = t * KVT + 32 * p;
            #pragma unroll
            for (int qt = 0; qt < 2; ++qt) {
                float psum = 0.f;
                int q = qbase + qt * 16 + l16;
                #pragma unroll
                for (int nt = 0; nt < 2; ++nt) {
                    float pv[4];
                    #pragma unroll
                    for (int i = 0; i < 4; ++i) {
                        float arg = fminf(fmaf(sv[qt][nt][i], SCL, -12.0f), 30.0f);
                        if (dm) {
                            int kv = kvb + nt * 16 + quad * 4 + i;
                            if (kv > q) arg = -1e30f;
                        }
                        pv[i] = fexp2(arg);
                        psum += pv[i];
                    }
                    sp[qt][nt][0] = pkbf(pv[0], pv[1]);
                    sp[qt][nt][1] = pkbf(pv[2], pv[3]);
                }
                ls[qt] += psum;
            }
            // O^T += V^T.P^T
            int qsel = quad & 2;
            bf16x8 f0 = xfrag(sp[0][0][0], sp[0][0][1], sp[0][1][0], sp[0][1][1], qsel);
            bf16x8 f1 = xfrag(sp[1][0][0], sp[1][0][1], sp[1][1][0], sp[1][1][1], qsel);
            __builtin_amdgcn_s_setprio(1);
            o[0][0] = __builtin_amdgcn_mfma_f32_16x16x32_bf16(av0, f0, o[0][0], 0, 0, 0);
            o[1][0] = __builtin_amdgcn_mfma_f32_16x16x32_bf16(av0, f1, o[1][0], 0, 0, 0);
            o[0][1] = __builtin_amdgcn_mfma_f32_16x16x32_bf16(av1, f0, o[0][1], 0, 0, 0);
            o[1][1] = __builtin_amdgcn_mfma_f32_16x16x32_bf16(av1, f1, o[1][1], 0, 0, 0);
            o[0][2] = __builtin_amdgcn_mfma_f32_16x16x32_bf16(av2, f0, o[0][2], 0, 0, 0);
            o[1][2] = __builtin_amdgcn_mfma_f32_16x16x32_bf16(av2, f1, o[1][2], 0, 0, 0);
            o[0][3] = __builtin_amdgcn_mfma_f32_16x16x32_bf16(av3, f0, o[0][3], 0, 0, 0);
            o[1][3] = __builtin_amdgcn_mfma_f32_16x16x32_bf16(av3, f1, o[1][3], 0, 0, 0);
            __builtin_amdgcn_s_setprio(0);
        }

        __syncthreads();   // own gl_lds drained (compiler vmcnt) -> trip t+1 staged
    }

    // merge the two kv-parity partials (additive: same fixed-max scale), normalize, store
    #pragma unroll
    for (int qt = 0; qt < 2; ++qt) {
        ls[qt] += __shfl_xor(ls[qt], 16);
        ls[qt] += __shfl_xor(ls[qt], 32);
    }
    float* mrg  = SMf;                 // [2 bands][32 q][68] floats = 17408B
    float* lbuf = SMf + 4352;          // [2 bands][32 q] floats

    if (p == 1) {
        #pragma unroll
        for (int qt = 0; qt < 2; ++qt)
            #pragma unroll
            for (int dt = 0; dt < 4; ++dt)
                *(f32x4*)&mrg[s_ * (32 * 68) + (qt * 16 + l16) * 68 + dt * 16 + quad * 4] = o[qt][dt];
        if (quad == 0) {
            lbuf[s_ * 32 + l16]      = ls[0];
            lbuf[s_ * 32 + 16 + l16] = ls[1];
        }
    }
    __syncthreads();
    if (p == 0) {
        #pragma unroll
        for (int qt = 0; qt < 2; ++qt) {
            float lt = ls[qt] + lbuf[s_ * 32 + qt * 16 + l16];
            float inv = 1.0f / lt;
            int q = qbase + qt * 16 + l16;
            if (isbf) {
                unsigned short* out = (unsigned short*)outv;
                #pragma unroll
                for (int dt = 0; dt < 4; ++dt) {
                    f32x4 m = *(const f32x4*)&mrg[s_ * (32 * 68) + (qt * 16 + l16) * 68 + dt * 16 + quad * 4];
                    u16x4 ov;
                    #pragma unroll
                    for (int i = 0; i < 4; ++i) ov[i] = f2b((o[qt][dt][i] + m[i]) * inv);
                    *(u16x4*)&out[(rowbase + q) * CDIM + h * HS + dt * 16 + quad * 4] = ov;
                }
            } else {
                float* out = (float*)outv;
                #pragma unroll
                for (int dt = 0; dt < 4; ++dt) {
                    f32x4 m = *(const f32x4*)&mrg[s_ * (32 * 68) + (qt * 16 + l16) * 68 + dt * 16 + quad * 4];
                    float4 ov;
                    ov.x = (o[qt][dt][0] + m[0]) * inv;
                    ov.y = (o[qt][dt][1] + m[1]) * inv;
                    ov.z = (o[qt][dt][2] + m[2]) * inv;
                    ov.w = (o[qt][dt][3] + m[3]) * inv;
                    *(float4*)&out[(rowbase + q) * CDIM + h * HS + dt * 16 + quad * 4] = ov;
                }
            }
        }
    }
}

extern "C" void kernel_launch(void* const* d_in, const int* in_sizes, int n_in,
                              void* d_out, int out_size, void* d_ws, size_t ws_size,
                              hipStream_t stream) {
    const void* x    = d_in[0];
    const void* w    = d_in[1];
    const void* bias = d_in[2];

    char* ws = (char*)d_ws;
    unsigned short* xb  = (unsigned short*)ws;                   // 8 MB (fp32 path only)
    unsigned short* wt  = (unsigned short*)(ws + (8u  << 20));   // 6 MB
    unsigned short* qk  = (unsigned short*)(ws + (16u << 20));   // 16 MB
    unsigned short* vtg = (unsigned short*)(ws + (32u << 20));   // 8 MB

    k_prep<<<2048, 256, 0, stream>>>(w, x, bias, wt, xb);
    k_gemm_qkv<<<dim3(24, 32), 256, 0, stream>>>(x, xb, bias, wt, qk, vtg);
    k_attn<<<dim3(32, 32), 256, 0, stream>>>(qk, vtg, bias, d_out);
}